// Round 1
// baseline (1317.958 us; speedup 1.0000x reference)
//
#include <hip/hip_runtime.h>
#include <math.h>

#define NFFT 1024
#define BLK  256

// LDS bank swizzle on float2 index: keeps contiguous reads conflict-free and
// spreads the strided Stockham writes (stages 0/1 would be 16-way otherwise).
__device__ __forceinline__ int phi(int i) { return i ^ ((i >> 4) & 15); }

__device__ __forceinline__ float2 cmulf(float2 a, float2 b) {
    return make_float2(a.x * b.x - a.y * b.y, a.x * b.y + a.y * b.x);
}

// One Stockham radix-4 stage. Reads src[t+256r], writes dst[q+s*(4p+r)].
// DIR=+1: forward (table holds e^{-2*pi*i*j/1024}); DIR=-1: inverse (conjugate).
template <int DIR>
__device__ __forceinline__ void stage4(const float2* src, float2* dst,
                                       const float2* tw, int st, int t) {
    const int s = 1 << (2 * st);
    const int e = t & ~(s - 1);      // e = s*p, twiddle exponent (< 256)
    float2 w1 = tw[e];
    if (DIR < 0) w1.y = -w1.y;
    const float2 w2 = cmulf(w1, w1);
    const float2 w3 = cmulf(w2, w1);

    const float2 a = src[phi(t)];
    const float2 b = src[phi(t + 256)];
    const float2 c = src[phi(t + 512)];
    const float2 d = src[phi(t + 768)];

    const float2 apc = make_float2(a.x + c.x, a.y + c.y);
    const float2 amc = make_float2(a.x - c.x, a.y - c.y);
    const float2 bpd = make_float2(b.x + d.x, b.y + d.y);
    const float2 bmd = make_float2(b.x - d.x, b.y - d.y);

    const float2 y0 = make_float2(apc.x + bpd.x, apc.y + bpd.y);
    const float2 y2 = make_float2(apc.x - bpd.x, apc.y - bpd.y);
    float2 y1, y3;
    if (DIR > 0) {
        y1 = make_float2(amc.x + bmd.y, amc.y - bmd.x);  // amc - i*bmd
        y3 = make_float2(amc.x - bmd.y, amc.y + bmd.x);  // amc + i*bmd
    } else {
        y1 = make_float2(amc.x - bmd.y, amc.y + bmd.x);
        y3 = make_float2(amc.x + bmd.y, amc.y - bmd.x);
    }

    const int base = t + 3 * e;      // q + 4*s*p
    dst[phi(base)]         = y0;
    dst[phi(base + s)]     = cmulf(y1, w1);
    dst[phi(base + 2 * s)] = cmulf(y2, w2);
    dst[phi(base + 3 * s)] = cmulf(y3, w3);
}

// 5 radix-4 stages: input in A (natural order), result lands in B.
template <int DIR>
__device__ __forceinline__ void fft5(float2* A, float2* B, const float2* tw, int t) {
    stage4<DIR>(A, B, tw, 0, t); __syncthreads();
    stage4<DIR>(B, A, tw, 1, t); __syncthreads();
    stage4<DIR>(A, B, tw, 2, t); __syncthreads();
    stage4<DIR>(B, A, tw, 3, t); __syncthreads();
    stage4<DIR>(A, B, tw, 4, t); __syncthreads();
}

__global__ __launch_bounds__(BLK)
void siva_kernel(const float* __restrict__ x,
                 const float* __restrict__ nu_p,
                 const float* __restrict__ dto_p,
                 const float* __restrict__ cr_p,
                 const int* __restrict__ nt_p,
                 const int* __restrict__ ns_p,
                 float* __restrict__ out) {
    __shared__ float2 A[NFFT];
    __shared__ float2 Bs[NFFT];
    __shared__ float2 TW[NFFT];
    __shared__ float2 SPEC[NFFT];

    const int b = blockIdx.x;
    const int t = threadIdx.x;

    const int nT   = nt_p[0];
    const int nsub = ns_p[0];

    const float nu  = (1.0f / (1.0f + expf(-nu_p[0])))  * (0.5f - 0.01f)  + 0.01f;
    const float dto = (1.0f / (1.0f + expf(-dto_p[0]))) * (0.1f - 0.001f) + 0.001f;
    const float cR  = (1.0f / (1.0f + expf(-cr_p[0])))  * (2.0f - 0.5f)   + 0.5f;
    const float dt   = dto / (float)nsub;
    const float dtcR = dt * cR;

    // Tables: twiddles W^j = e^{-2*pi*i*j/1024}, and spectral-update coeffs.
    for (int r = 0; r < 4; ++r) {
        const int j = t + 256 * r;
        const float tt = (float)j * (1.0f / 512.0f);        // angle in units of pi
        TW[j] = make_float2(cospif(tt), -sinpif(tt));
        const float kk = (j <= 512) ? (float)j : (float)(j - 1024);  // signed freq
        const float ka = fabsf(kk);
        const float q  = 1.0f - dtcR * (ka - nu * ka * ka);
        const float ai = (1.0f / q) * (1.0f / 1024.0f);     // fold 1/N of inverse FFT
        SPEC[j] = make_float2(ai, dt * kk * ai);
    }

    // Load d = x[b, :, 0]
    for (int r = 0; r < 4; ++r) {
        const int j = t + 256 * r;
        A[phi(j)] = make_float2(x[b * NFFT + j], 0.0f);
    }
    __syncthreads();  // tables + A ready

    // d_to_u: u = Re(ifft(i * kk * fft(d)) / N)
    fft5<1>(A, Bs, TW, t);
    for (int r = 0; r < 4; ++r) {
        const int j = t + 256 * r;
        const float kk = (j <= 512) ? (float)j : (float)(j - 1024);
        const float sc = kk * (1.0f / 1024.0f);
        const float2 D = Bs[phi(j)];
        Bs[phi(j)] = make_float2(-D.y * sc, D.x * sc);  // i*kk*D (pointwise, self idx)
    }
    fft5<-1>(Bs, A, TW, t);  // u in A (.x)

    for (int ot = 0; ot < nT; ++ot) {
        for (int ss = 0; ss < nsub; ++ss) {
            // pack z = u + i*0.5u^2 (in place, self indices)
            for (int r = 0; r < 4; ++r) {
                const int j = t + 256 * r;
                const float u = A[phi(j)].x;
                A[phi(j)] = make_float2(u, 0.5f * u * u);
            }
            fft5<1>(A, Bs, TW, t);  // Z in Bs

            // unpack Hermitian halves + spectral update:
            // newhat = (uhat - dt*i*kk*u2hat) / q / N
            float2 nh[4];
            for (int r = 0; r < 4; ++r) {
                const int j  = t + 256 * r;
                const int jm = (NFFT - j) & (NFFT - 1);
                const float2 Zj = Bs[phi(j)];
                const float2 Zm = Bs[phi(jm)];
                const float uhx = 0.5f * (Zj.x + Zm.x);
                const float uhy = 0.5f * (Zj.y - Zm.y);
                const float u2x = 0.5f * (Zj.y + Zm.y);
                const float u2y = -0.5f * (Zj.x - Zm.x);
                const float2 ab = SPEC[j];
                nh[r] = make_float2(ab.x * uhx + ab.y * u2y,
                                    ab.x * uhy - ab.y * u2x);
            }
            __syncthreads();  // mirror reads done before overwrite
            for (int r = 0; r < 4; ++r) {
                Bs[phi(t + 256 * r)] = nh[r];
            }
            fft5<-1>(Bs, A, TW, t);  // u_new in A
        }

        // snapshot: u_to_d, write output, restore u
        float ur[4];
        for (int r = 0; r < 4; ++r) {
            const int j = t + 256 * r;
            ur[r] = A[phi(j)].x;
            A[phi(j)] = make_float2(ur[r], 0.0f);  // zero imag junk (self idx)
        }
        fft5<1>(A, Bs, TW, t);  // U in Bs
        for (int r = 0; r < 4; ++r) {
            const int j = t + 256 * r;
            const float kk = (j <= 512) ? (float)j : (float)(j - 1024);
            const float c  = (j == 0) ? 0.0f : (1.0f / (1024.0f * kk));
            const float2 U = Bs[phi(j)];
            Bs[phi(j)] = make_float2(U.y * c, -U.x * c);  // -i*U/(N*kk)
        }
        fft5<-1>(Bs, A, TW, t);  // dsol in A
        for (int r = 0; r < 4; ++r) {
            const int j = t + 256 * r;
            out[(b * NFFT + j) * nT + ot] = A[phi(j)].x;
            A[phi(j)] = make_float2(ur[r], 0.0f);  // restore u for next outer step
        }
        __syncthreads();
    }
}

extern "C" void kernel_launch(void* const* d_in, const int* in_sizes, int n_in,
                              void* d_out, int out_size, void* d_ws, size_t ws_size,
                              hipStream_t stream) {
    const float* x     = (const float*)d_in[0];
    const float* nu_p  = (const float*)d_in[1];
    const float* dto_p = (const float*)d_in[2];
    const float* cr_p  = (const float*)d_in[3];
    const int*   nt_p  = (const int*)d_in[4];
    const int*   ns_p  = (const int*)d_in[5];
    float* out = (float*)d_out;

    const int B = in_sizes[0] / NFFT;  // C == 1
    siva_kernel<<<B, BLK, 0, stream>>>(x, nu_p, dto_p, cr_p, nt_p, ns_p, out);
}

// Round 2
// 1212.755 us; speedup vs baseline: 1.0867x; 1.0867x over previous
//
#include <hip/hip_runtime.h>
#include <math.h>

#define NFFT 1024
#define BLK  256

__global__ __launch_bounds__(BLK)
void siva_kernel(const float* __restrict__ x,
                 const float* __restrict__ nu_p,
                 const float* __restrict__ dto_p,
                 const float* __restrict__ cr_p,
                 const int* __restrict__ nt_p,
                 const int* __restrict__ ns_p,
                 float* __restrict__ out) {
    // Three separate LDS buffers -> only 3 __syncthreads per substep
    // (write->barrier->read; the read-before-next-overwrite hazard is covered
    //  by the other two buffers' barriers in between).
    __shared__ float2 bufT[NFFT];   // forward transpose
    __shared__ float2 bufU[NFFT];   // Hermitian-mirror exchange
    __shared__ float2 bufT2[NFFT];  // inverse transpose

    const int t = threadIdx.x;
    const int b = blockIdx.x;
    const int l = t & 63;        // lane
    const int w = t >> 6;        // wave 0..3
    const int R = (int)(__brev((unsigned)l) >> 26);  // rev6(l)

    const int nT   = nt_p[0];
    const int nsub = ns_p[0];

    const float nu  = (1.0f / (1.0f + expf(-nu_p[0])))  * (0.5f - 0.01f)  + 0.01f;
    const float dto = (1.0f / (1.0f + expf(-dto_p[0]))) * (0.1f - 0.001f) + 0.001f;
    const float cR  = (1.0f / (1.0f + expf(-cr_p[0])))  * (2.0f - 0.5f)   + 0.5f;
    const float dt   = dto / (float)nsub;
    const float dtcR = dt * cR;

    // ---- persistent per-thread constants ----
    // Stage A twiddles W1024^{t*r}
    float2 TA[3];
    #pragma unroll
    for (int r = 1; r <= 3; ++r) {
        const float a = (float)(t * r) * (1.0f / 512.0f);   // angle in pi units
        TA[r - 1] = make_float2(cospif(a), -sinpif(a));
    }
    // Stage B twiddles W256^{l*r}
    float2 TB[3];
    #pragma unroll
    for (int r = 1; r <= 3; ++r) {
        const float a = (float)(l * r) * (1.0f / 128.0f);
        TB[r - 1] = make_float2(cospif(a), -sinpif(a));
    }
    // Lane-FFT (64-pt radix-2) per-stage constants.
    // fwd DIF stage h=32>>s: high lanes multiply by W_{2h}^{l mod h}; sgn=-1.
    // inv DIT stage h=1<<s : wi = +-conj(W_{2h}^{l mod h}).
    float2 wf[6]; float sg[6]; float2 wi[6];
    #pragma unroll
    for (int s = 0; s < 6; ++s) {
        const int h = 32 >> s;
        const int lm = l & (h - 1);
        const bool hi = (l & h) != 0;
        const float a = (float)(lm * (32 / h)) * (1.0f / 32.0f);
        wf[s] = hi ? make_float2(cospif(a), -sinpif(a)) : make_float2(1.0f, 0.0f);
        sg[s] = hi ? -1.0f : 1.0f;
        const int h2 = 1 << s;
        const int lm2 = l & (h2 - 1);
        const float a2 = (float)lm2 / (float)h2;            // conj => +angle
        float2 wb = make_float2(cospif(a2), sinpif(a2));
        if ((l & h2) != 0) { wb.x = -wb.x; wb.y = -wb.y; }
        wi[s] = wb;
    }
    // Spectral coefficients. k = 16*rev6(l) + 4*r2 + w.
    // newhat = P*Z + Q*conj(Zm) with REAL P=(a - dt*k*a)/2, Q=(a + dt*k*a)/2.
    float Pc[4], Qc[4], csn[4], si[4];
    int mirA[4];
    #pragma unroll
    for (int r2 = 0; r2 < 4; ++r2) {
        const int k = 16 * R + 4 * r2 + w;
        const float kk = (k <= 512) ? (float)k : (float)(k - 1024);
        const float ka = fabsf(kk);
        const float q = 1.0f - dtcR * (ka - nu * ka * ka);
        const float aco = (1.0f / q) * (1.0f / 1024.0f);    // 1/(q*N)
        const float m = dt * kk * aco;
        Pc[r2] = 0.5f * (aco - m);
        Qc[r2] = 0.5f * (aco + m);
        csn[r2] = (k == 0) ? 0.0f : (1.0f / (1024.0f * kk));
        si[r2]  = kk * (1.0f / 1024.0f);
        int wm, r2m, lmr;
        if (w == 0 && r2 == 0) {
            wm = 0; r2m = 0;
            lmr = (int)(__brev((unsigned)((64 - R) & 63)) >> 26);
        } else if (w == 0) {
            wm = 0; r2m = 4 - r2; lmr = 63 - l;
        } else {
            wm = 4 - w; r2m = 3 - r2; lmr = 63 - l;
        }
        mirA[r2] = wm * 256 + r2m * 64 + lmr;   // bufU layout [w][r2][l]
    }

    // radix-4 DIF butterfly + twiddles (forward)
    auto radix4f = [](float2& z0, float2& z1, float2& z2, float2& z3,
                      const float2 T1, const float2 T2, const float2 T3) {
        const float2 apc = make_float2(z0.x + z2.x, z0.y + z2.y);
        const float2 amc = make_float2(z0.x - z2.x, z0.y - z2.y);
        const float2 bpd = make_float2(z1.x + z3.x, z1.y + z3.y);
        const float2 bmd = make_float2(z1.x - z3.x, z1.y - z3.y);
        const float2 y0 = make_float2(apc.x + bpd.x, apc.y + bpd.y);
        const float2 y1 = make_float2(amc.x + bmd.y, amc.y - bmd.x);  // amc - i*bmd
        const float2 y2 = make_float2(apc.x - bpd.x, apc.y - bpd.y);
        const float2 y3 = make_float2(amc.x - bmd.y, amc.y + bmd.x);  // amc + i*bmd
        z0 = y0;
        z1 = make_float2(y1.x * T1.x - y1.y * T1.y, y1.x * T1.y + y1.y * T1.x);
        z2 = make_float2(y2.x * T2.x - y2.y * T2.y, y2.x * T2.y + y2.y * T2.x);
        z3 = make_float2(y3.x * T3.x - y3.y * T3.y, y3.x * T3.y + y3.y * T3.x);
    };

    // forward FFT-1024: natural (t,j) layout -> spectral (w,l,r2) layout
    auto fwd = [&](float2 z[4]) {
        radix4f(z[0], z[1], z[2], z[3], TA[0], TA[1], TA[2]);
        bufT[t]       = z[0];
        bufT[256 + t] = z[1];
        bufT[512 + t] = z[2];
        bufT[768 + t] = z[3];
        __syncthreads();
        z[0] = bufT[w * 256 + l];
        z[1] = bufT[w * 256 + 64 + l];
        z[2] = bufT[w * 256 + 128 + l];
        z[3] = bufT[w * 256 + 192 + l];
        radix4f(z[0], z[1], z[2], z[3], TB[0], TB[1], TB[2]);
        #pragma unroll
        for (int s = 0; s < 6; ++s) {
            const int h = 32 >> s;
            #pragma unroll
            for (int r = 0; r < 4; ++r) {
                const float bx = __shfl_xor(z[r].x, h);
                const float by = __shfl_xor(z[r].y, h);
                const float tx = fmaf(sg[s], z[r].x, bx);
                const float ty = fmaf(sg[s], z[r].y, by);
                z[r].x = tx * wf[s].x - ty * wf[s].y;
                z[r].y = tx * wf[s].y + ty * wf[s].x;
            }
        }
    };

    // inverse FFT-1024: spectral layout -> natural layout, REAL part only.
    auto inv = [&](float2 z[4], float ur[4]) {
        #pragma unroll
        for (int s = 0; s < 6; ++s) {
            const int h = 1 << s;
            const bool hi = (l & h) != 0;
            #pragma unroll
            for (int r = 0; r < 4; ++r) {
                const float bx = __shfl_xor(z[r].x, h);
                const float by = __shfl_xor(z[r].y, h);
                const float px = hi ? z[r].x : bx;
                const float py = hi ? z[r].y : by;
                const float qx = hi ? bx : z[r].x;
                const float qy = hi ? by : z[r].y;
                z[r].x = qx + px * wi[s].x - py * wi[s].y;
                z[r].y = qy + px * wi[s].y + py * wi[s].x;
            }
        }
        // inverse stage B: g = z * conj(TB); inverse radix-4 (i^{+m*r2})
        const float2 g0 = z[0];
        const float2 g1 = make_float2(z[1].x * TB[0].x + z[1].y * TB[0].y,
                                      z[1].y * TB[0].x - z[1].x * TB[0].y);
        const float2 g2 = make_float2(z[2].x * TB[1].x + z[2].y * TB[1].y,
                                      z[2].y * TB[1].x - z[2].x * TB[1].y);
        const float2 g3 = make_float2(z[3].x * TB[2].x + z[3].y * TB[2].y,
                                      z[3].y * TB[2].x - z[3].x * TB[2].y);
        const float2 apc = make_float2(g0.x + g2.x, g0.y + g2.y);
        const float2 amc = make_float2(g0.x - g2.x, g0.y - g2.y);
        const float2 bpd = make_float2(g1.x + g3.x, g1.y + g3.y);
        const float2 bmd = make_float2(g1.x - g3.x, g1.y - g3.y);
        bufT2[w * 256 + l]       = make_float2(apc.x + bpd.x, apc.y + bpd.y);
        bufT2[w * 256 + 64 + l]  = make_float2(amc.x - bmd.y, amc.y + bmd.x); // +i*bmd
        bufT2[w * 256 + 128 + l] = make_float2(apc.x - bpd.x, apc.y - bpd.y);
        bufT2[w * 256 + 192 + l] = make_float2(amc.x + bmd.y, amc.y - bmd.x); // -i*bmd
        __syncthreads();
        const float2 h0 = bufT2[t];
        const float2 h1 = bufT2[256 + t];
        const float2 h2 = bufT2[512 + t];
        const float2 h3 = bufT2[768 + t];
        // g_j = h_j * conj(TA_j); u_j = Re(sum_r g_r i^{j*r})
        const float g1x = h1.x * TA[0].x + h1.y * TA[0].y;
        const float g1y = h1.y * TA[0].x - h1.x * TA[0].y;
        const float g2x = h2.x * TA[1].x + h2.y * TA[1].y;
        const float g3x = h3.x * TA[2].x + h3.y * TA[2].y;
        const float g3y = h3.y * TA[2].x - h3.x * TA[2].y;
        ur[0] = h0.x + g1x + g2x + g3x;
        ur[1] = h0.x - g1y - g2x + g3y;
        ur[2] = h0.x - g1x + g2x - g3x;
        ur[3] = h0.x + g1y - g2x - g3y;
    };

    // ---- init: d_to_u ----
    float2 z[4];
    float ur[4];
    #pragma unroll
    for (int j = 0; j < 4; ++j)
        z[j] = make_float2(x[b * NFFT + t + 256 * j], 0.0f);
    fwd(z);
    #pragma unroll
    for (int r2 = 0; r2 < 4; ++r2) {
        const float zx = z[r2].x, zy = z[r2].y;
        z[r2] = make_float2(-zy * si[r2], zx * si[r2]);   // i*k*Z / N
    }
    inv(z, ur);

    for (int ot = 0; ot < nT; ++ot) {
        for (int ss = 0; ss < nsub; ++ss) {
            #pragma unroll
            for (int j = 0; j < 4; ++j)
                z[j] = make_float2(ur[j], 0.5f * ur[j] * ur[j]);
            fwd(z);
            // Hermitian-mirror exchange (cross-wave) + spectral update
            bufU[w * 256 + l]       = z[0];
            bufU[w * 256 + 64 + l]  = z[1];
            bufU[w * 256 + 128 + l] = z[2];
            bufU[w * 256 + 192 + l] = z[3];
            __syncthreads();
            #pragma unroll
            for (int r2 = 0; r2 < 4; ++r2) {
                const float2 zm = bufU[mirA[r2]];
                z[r2] = make_float2(Pc[r2] * z[r2].x + Qc[r2] * zm.x,
                                    Pc[r2] * z[r2].y - Qc[r2] * zm.y);
            }
            inv(z, ur);
        }
        // snapshot: u_to_d (pointwise in k, no mirror needed)
        #pragma unroll
        for (int j = 0; j < 4; ++j)
            z[j] = make_float2(ur[j], 0.0f);
        fwd(z);
        #pragma unroll
        for (int r2 = 0; r2 < 4; ++r2) {
            const float zx = z[r2].x, zy = z[r2].y;
            z[r2] = make_float2(zy * csn[r2], -zx * csn[r2]);  // -i*Z/(N*k)
        }
        float dr[4];
        inv(z, dr);
        #pragma unroll
        for (int j = 0; j < 4; ++j)
            out[(b * NFFT + t + 256 * j) * nT + ot] = dr[j];
    }
}

extern "C" void kernel_launch(void* const* d_in, const int* in_sizes, int n_in,
                              void* d_out, int out_size, void* d_ws, size_t ws_size,
                              hipStream_t stream) {
    const float* x     = (const float*)d_in[0];
    const float* nu_p  = (const float*)d_in[1];
    const float* dto_p = (const float*)d_in[2];
    const float* cr_p  = (const float*)d_in[3];
    const int*   nt_p  = (const int*)d_in[4];
    const int*   ns_p  = (const int*)d_in[5];
    float* out = (float*)d_out;

    const int B = in_sizes[0] / NFFT;  // C == 1
    siva_kernel<<<B, BLK, 0, stream>>>(x, nu_p, dto_p, cr_p, nt_p, ns_p, out);
}

// Round 4
// 1003.814 us; speedup vs baseline: 1.3129x; 1.2081x over previous
//
#include <hip/hip_runtime.h>
#include <math.h>

#define NFFT 1024
#define BLK  256

// quad_perm DPP (VALU pipe). 0xB1 = lane^1, 0x4E = lane^2, 0x1B = lane^3.
template <int CTRL>
__device__ __forceinline__ float dppf(float v) {
    return __int_as_float(__builtin_amdgcn_update_dpp(
        0, __float_as_int(v), CTRL, 0xF, 0xF, true));
}

__global__ __launch_bounds__(BLK)
void siva_kernel(const float* __restrict__ x,
                 const float* __restrict__ nu_p,
                 const float* __restrict__ dto_p,
                 const float* __restrict__ cr_p,
                 const int* __restrict__ nt_p,
                 const int* __restrict__ ns_p,
                 float* __restrict__ out) {
    __shared__ float2 bufT[NFFT];    // forward transpose
    __shared__ float2 bufT2[NFFT];   // inverse transpose

    const int t = threadIdx.x;
    const int b = blockIdx.x;
    const int l = t & 63;
    const int w = t >> 6;
    // radix-4 digit reversal of lane: l = 16a+4b2+c -> R = a + 4*b2 + 16*c
    const int R = (l >> 4) | (l & 12) | ((l & 3) << 4);

    const int nT   = nt_p[0];
    const int nsub = ns_p[0];

    const float nu  = (1.0f / (1.0f + expf(-nu_p[0])))  * (0.5f - 0.01f)  + 0.01f;
    const float dto = (1.0f / (1.0f + expf(-dto_p[0]))) * (0.1f - 0.001f) + 0.001f;
    const float cR  = (1.0f / (1.0f + expf(-cr_p[0])))  * (2.0f - 0.5f)   + 0.5f;
    const float dt   = dto / (float)nsub;
    const float dtcR = dt * cR;

    // Stage A twiddles W1024^{t*r}; Stage B twiddles W256^{l*r}
    float2 TA[3], TB[3];
    #pragma unroll
    for (int r = 1; r <= 3; ++r) {
        const float a = (float)(t * r) * (1.0f / 512.0f);   // pi units
        TA[r - 1] = make_float2(cospif(a), -sinpif(a));
        const float a2 = (float)(l * r) * (1.0f / 128.0f);
        TB[r - 1] = make_float2(cospif(a2), -sinpif(a2));
    }

    // Lane-FFT radix-4 per-stage per-lane weights.
    // Forward stage (stride h): lane keeps y_a = W_{4h}^{a*m} * sum_d W_4^{(d^a)a} u_d
    // Inverse stage (stride h): x_a = sum_d W_4^{-a(a^d)} W_{4h}^{+(a^d)m} u_d
    // (u_d = value from lane l^(h*d); all weights per-lane constants.)
    float2 GF[3][4], GI[3][4];
    {
        const int hs[3] = {16, 4, 1};
        #pragma unroll
        for (int s = 0; s < 3; ++s) {
            const int h = hs[s];
            const int a = (l / h) & 3;
            const int m = l % h;
            const float invM = 1.0f / (float)(4 * h);
            #pragma unroll
            for (int d = 0; d < 4; ++d) {
                const int e4 = ((d ^ a) * a) & 3;
                const float angF = 0.5f * (float)e4
                                 + 2.0f * (float)(a * m) * invM;      // pi units
                GF[s][d] = make_float2(cospif(angF), -sinpif(angF));
                const float angI = 0.5f * (float)e4
                                 + 2.0f * (float)((d ^ a) * m) * invM;
                GI[2 - s][d] = make_float2(cospif(angI), sinpif(angI));
            }
        }
    }

    // Spectral constants. k = 16*R + 4*r2 + w.
    // Substep: unew = Re(ifft(S .* fft(u + i*0.5u^2))),
    //   S_k = (1 - dt*kk)/(q_k*N), kk -> 0 at the self-mirror bins k=0,512.
    float Sc[4], csn[4], si[4];
    #pragma unroll
    for (int r2 = 0; r2 < 4; ++r2) {
        const int k = 16 * R + 4 * r2 + w;
        const float kk = (k <= 512) ? (float)k : (float)(k - 1024);
        const float ka = fabsf(kk);
        const float q  = 1.0f - dtcR * (ka - nu * ka * ka);
        const float a  = (1.0f / q) * (1.0f / 1024.0f);
        const float kkS = (k == 0 || k == 512) ? 0.0f : kk;
        Sc[r2]  = a * (1.0f - dt * kkS);
        csn[r2] = (k == 0) ? 0.0f : (1.0f / (1024.0f * kk));
        si[r2]  = kk * (1.0f / 1024.0f);
    }

    auto radix4f = [](float2& z0, float2& z1, float2& z2, float2& z3,
                      const float2 T1, const float2 T2, const float2 T3) {
        const float2 apc = make_float2(z0.x + z2.x, z0.y + z2.y);
        const float2 amc = make_float2(z0.x - z2.x, z0.y - z2.y);
        const float2 bpd = make_float2(z1.x + z3.x, z1.y + z3.y);
        const float2 bmd = make_float2(z1.x - z3.x, z1.y - z3.y);
        const float2 y0 = make_float2(apc.x + bpd.x, apc.y + bpd.y);
        const float2 y1 = make_float2(amc.x + bmd.y, amc.y - bmd.x);
        const float2 y2 = make_float2(apc.x - bpd.x, apc.y - bpd.y);
        const float2 y3 = make_float2(amc.x - bmd.y, amc.y + bmd.x);
        z0 = y0;
        z1 = make_float2(y1.x * T1.x - y1.y * T1.y, y1.x * T1.y + y1.y * T1.x);
        z2 = make_float2(y2.x * T2.x - y2.y * T2.y, y2.x * T2.y + y2.y * T2.x);
        z3 = make_float2(y3.x * T3.x - y3.y * T3.y, y3.x * T3.y + y3.y * T3.x);
    };

    // y = g0*z0 + g1*z1 + g2*z2 + g3*z3 (complex)
    auto c4 = [](float2 g0, float2 z0, float2 g1, float2 z1,
                 float2 g2, float2 z2, float2 g3, float2 z3) -> float2 {
        float xx = g0.x * z0.x;      xx = fmaf(-g0.y, z0.y, xx);
        xx = fmaf(g1.x, z1.x, xx);   xx = fmaf(-g1.y, z1.y, xx);
        xx = fmaf(g2.x, z2.x, xx);   xx = fmaf(-g2.y, z2.y, xx);
        xx = fmaf(g3.x, z3.x, xx);   xx = fmaf(-g3.y, z3.y, xx);
        float yy = g0.x * z0.y;      yy = fmaf(g0.y, z0.x, yy);
        yy = fmaf(g1.x, z1.y, yy);   yy = fmaf(g1.y, z1.x, yy);
        yy = fmaf(g2.x, z2.y, yy);   yy = fmaf(g2.y, z2.x, yy);
        yy = fmaf(g3.x, z3.y, yy);   yy = fmaf(g3.y, z3.x, yy);
        return make_float2(xx, yy);
    };

    auto lstage_shfl = [&c4](float2 z[4], const float2* G, int h) {
        #pragma unroll
        for (int r = 0; r < 4; ++r) {
            const float2 u1 = make_float2(__shfl_xor(z[r].x, h),
                                          __shfl_xor(z[r].y, h));
            const float2 u2 = make_float2(__shfl_xor(z[r].x, 2 * h),
                                          __shfl_xor(z[r].y, 2 * h));
            const float2 u3 = make_float2(__shfl_xor(z[r].x, 3 * h),
                                          __shfl_xor(z[r].y, 3 * h));
            z[r] = c4(G[0], z[r], G[1], u1, G[2], u2, G[3], u3);
        }
    };
    auto lstage_dpp = [&c4](float2 z[4], const float2* G) {
        #pragma unroll
        for (int r = 0; r < 4; ++r) {
            const float2 u1 = make_float2(dppf<0xB1>(z[r].x), dppf<0xB1>(z[r].y));
            const float2 u2 = make_float2(dppf<0x4E>(z[r].x), dppf<0x4E>(z[r].y));
            const float2 u3 = make_float2(dppf<0x1B>(z[r].x), dppf<0x1B>(z[r].y));
            z[r] = c4(G[0], z[r], G[1], u1, G[2], u2, G[3], u3);
        }
    };

    // forward FFT-1024: natural layout -> spectral (k = 16R + 4r2 + w)
    auto fwd = [&](float2 z[4]) {
        radix4f(z[0], z[1], z[2], z[3], TA[0], TA[1], TA[2]);
        bufT[t] = z[0]; bufT[256 + t] = z[1];
        bufT[512 + t] = z[2]; bufT[768 + t] = z[3];
        __syncthreads();
        z[0] = bufT[w * 256 + l];       z[1] = bufT[w * 256 + 64 + l];
        z[2] = bufT[w * 256 + 128 + l]; z[3] = bufT[w * 256 + 192 + l];
        radix4f(z[0], z[1], z[2], z[3], TB[0], TB[1], TB[2]);
        lstage_shfl(z, GF[0], 16);
        lstage_shfl(z, GF[1], 4);
        lstage_dpp (z, GF[2]);
    };

    // inverse FFT-1024: spectral layout -> natural, REAL part only
    auto inv = [&](float2 z[4], float ur[4]) {
        lstage_dpp (z, GI[0]);
        lstage_shfl(z, GI[1], 4);
        lstage_shfl(z, GI[2], 16);
        // inverse stage B: g = z*conj(TB), inverse radix-4
        const float2 g0 = z[0];
        const float2 g1 = make_float2(z[1].x * TB[0].x + z[1].y * TB[0].y,
                                      z[1].y * TB[0].x - z[1].x * TB[0].y);
        const float2 g2 = make_float2(z[2].x * TB[1].x + z[2].y * TB[1].y,
                                      z[2].y * TB[1].x - z[2].x * TB[1].y);
        const float2 g3 = make_float2(z[3].x * TB[2].x + z[3].y * TB[2].y,
                                      z[3].y * TB[2].x - z[3].x * TB[2].y);
        const float2 apc = make_float2(g0.x + g2.x, g0.y + g2.y);
        const float2 amc = make_float2(g0.x - g2.x, g0.y - g2.y);
        const float2 bpd = make_float2(g1.x + g3.x, g1.y + g3.y);
        const float2 bmd = make_float2(g1.x - g3.x, g1.y - g3.y);
        bufT2[w * 256 + l]       = make_float2(apc.x + bpd.x, apc.y + bpd.y);
        bufT2[w * 256 + 64 + l]  = make_float2(amc.x - bmd.y, amc.y + bmd.x);
        bufT2[w * 256 + 128 + l] = make_float2(apc.x - bpd.x, apc.y - bpd.y);
        bufT2[w * 256 + 192 + l] = make_float2(amc.x + bmd.y, amc.y - bmd.x);
        __syncthreads();
        const float2 h0 = bufT2[t];
        const float2 h1 = bufT2[256 + t];
        const float2 h2 = bufT2[512 + t];
        const float2 h3 = bufT2[768 + t];
        const float g1x = h1.x * TA[0].x + h1.y * TA[0].y;
        const float g1y = h1.y * TA[0].x - h1.x * TA[0].y;
        const float g2x = h2.x * TA[1].x + h2.y * TA[1].y;
        const float g3x = h3.x * TA[2].x + h3.y * TA[2].y;
        const float g3y = h3.y * TA[2].x - h3.x * TA[2].y;
        ur[0] = h0.x + g1x + g2x + g3x;
        ur[1] = h0.x - g1y - g2x + g3y;
        ur[2] = h0.x - g1x + g2x - g3x;
        ur[3] = h0.x + g1y - g2x - g3y;
    };

    // ---- init: d_to_u ----
    float2 z[4];
    float ur[4];
    #pragma unroll
    for (int j = 0; j < 4; ++j)
        z[j] = make_float2(x[b * NFFT + t + 256 * j], 0.0f);
    fwd(z);
    #pragma unroll
    for (int r2 = 0; r2 < 4; ++r2) {
        const float zx = z[r2].x, zy = z[r2].y;
        z[r2] = make_float2(-zy * si[r2], zx * si[r2]);   // i*k*Z / N
    }
    inv(z, ur);

    for (int ot = 0; ot < nT; ++ot) {
        for (int ss = 0; ss < nsub; ++ss) {
            #pragma unroll
            for (int j = 0; j < 4; ++j)
                z[j] = make_float2(ur[j], 0.5f * ur[j] * ur[j]);
            fwd(z);
            #pragma unroll
            for (int r2 = 0; r2 < 4; ++r2) {
                z[r2].x *= Sc[r2];
                z[r2].y *= Sc[r2];
            }
            inv(z, ur);
        }
        // snapshot: u_to_d
        #pragma unroll
        for (int j = 0; j < 4; ++j)
            z[j] = make_float2(ur[j], 0.0f);
        fwd(z);
        #pragma unroll
        for (int r2 = 0; r2 < 4; ++r2) {
            const float zx = z[r2].x, zy = z[r2].y;
            z[r2] = make_float2(zy * csn[r2], -zx * csn[r2]);  // -i*Z/(N*k)
        }
        float dr[4];
        inv(z, dr);
        #pragma unroll
        for (int j = 0; j < 4; ++j)
            out[(b * NFFT + t + 256 * j) * nT + ot] = dr[j];
    }
}

extern "C" void kernel_launch(void* const* d_in, const int* in_sizes, int n_in,
                              void* d_out, int out_size, void* d_ws, size_t ws_size,
                              hipStream_t stream) {
    const float* x     = (const float*)d_in[0];
    const float* nu_p  = (const float*)d_in[1];
    const float* dto_p = (const float*)d_in[2];
    const float* cr_p  = (const float*)d_in[3];
    const int*   nt_p  = (const int*)d_in[4];
    const int*   ns_p  = (const int*)d_in[5];
    float* out = (float*)d_out;

    const int B = in_sizes[0] / NFFT;  // C == 1
    siva_kernel<<<B, BLK, 0, stream>>>(x, nu_p, dto_p, cr_p, nt_p, ns_p, out);
}